// Round 2
// baseline (1433.681 us; speedup 1.0000x reference)
//
#include <hip/hip_runtime.h>

typedef _Float16 half_t;
typedef __attribute__((ext_vector_type(8))) _Float16 half8;
typedef __attribute__((ext_vector_type(4))) _Float16 half4;
typedef __attribute__((ext_vector_type(4))) float float4v;
typedef __attribute__((ext_vector_type(4))) int int4v;

#define NROWS 16384
#define HIDDIM 64

static __device__ __forceinline__ half_t f2h(float f) { return (half_t)f; }

static __device__ __forceinline__ float4v mfma16(half8 a, half8 b, float4v c) {
  return __builtin_amdgcn_mfma_f32_16x16x32_f16(a, b, c, 0, 0, 0);
}

// ---------------- P1: pack weights (fp16) + combined bias -------------------
__global__ void prep_wb(const float* __restrict__ Wxi, const float* __restrict__ Whi,
                        const float* __restrict__ Wxf, const float* __restrict__ Whf,
                        const float* __restrict__ Wxo, const float* __restrict__ Who,
                        const float* __restrict__ Wxc, const float* __restrict__ Whc,
                        const float* __restrict__ bxi, const float* __restrict__ bhi,
                        const float* __restrict__ bxf, const float* __restrict__ bhf,
                        const float* __restrict__ bxo, const float* __restrict__ bho,
                        const float* __restrict__ bxc, const float* __restrict__ bhc,
                        half_t* __restrict__ Wc, float* __restrict__ biasc) {
  int gid = blockIdx.x * 256 + threadIdx.x;
  const float* Wx[4] = {Wxi, Wxf, Wxo, Wxc};
  const float* Wh[4] = {Whi, Whf, Who, Whc};
  const float* bx[4] = {bxi, bxf, bxo, bxc};
  const float* bh[4] = {bhi, bhf, bho, bhc};
  if (gid < 32768) {
    int n = gid >> 7, k = gid & 127;
    int gate = n >> 6, h = n & 63;
    float v = (k < 64) ? Wx[gate][h * 64 + k] : Wh[gate][h * 64 + (k - 64)];
    Wc[gid] = f2h(v);                        // Wc[n][k], row-major, 128 wide
  } else if (gid < 33024) {
    int n = gid - 32768, gate = n >> 6, h = n & 63;
    biasc[n] = bx[gate][h] + bh[gate][h];
  }
}

// ---------------- P2: Bt[n][r] = fp16(Ht_1[r][n])  (transpose) --------------
__global__ __launch_bounds__(256) void prep_bt(const float* __restrict__ Ht_1,
                                               half_t* __restrict__ Bt) {
  __shared__ float tile[64][65];
  int t = threadIdx.x;
  int r0 = blockIdx.x * 64;
#pragma unroll
  for (int i = 0; i < 16; ++i) {
    int idx = i * 256 + t;
    int row = idx >> 6, col = idx & 63;
    tile[row][col] = Ht_1[(size_t)(r0 + row) * 64 + col];
  }
  __syncthreads();
#pragma unroll
  for (int i = 0; i < 16; ++i) {
    int idx = i * 256 + t;
    int n = idx >> 6, c = idx & 63;
    Bt[(size_t)n * NROWS + r0 + c] = f2h(tile[c][n]);
  }
}

// ---------------- G: g = adj @ Ht_1  (fp16 MFMA, HBM-streaming) -------------
// 256 blocks x 512 threads; block = 64 rows of adj; BK = 64.
// LDS stride 88 halves (176 B): 16B-aligned fragment reads.
#define LDSTRIDE 88
__global__ __launch_bounds__(512) void gconv(const float* __restrict__ adj,
                                             const half_t* __restrict__ Bt,
                                             float* __restrict__ g) {
  __shared__ half_t As[64 * LDSTRIDE];
  __shared__ half_t Bs[64 * LDSTRIDE];
  const int t = threadIdx.x;
  const int lane = t & 63;
  const int wave = t >> 6;
  const int m0 = blockIdx.x * 64;

  // A staging: thread covers rows ar0 and ar0+32, float4 chunk akc
  const int ar0 = t >> 4;          // 0..31
  const int akc = t & 15;          // 16 float4 per 64-wide row
  const float* aptr = adj + (size_t)(m0 + ar0) * NROWS + akc * 4;
  // B staging: thread covers fp16 row bn, 16B chunk bc
  const int bn = t >> 3;           // 0..63
  const int bc = t & 7;
  const half_t* bptr = Bt + (size_t)bn * NROWS + bc * 8;

  const int quad = lane >> 4;
  const int l15 = lane & 15;
  const int mrow = (wave & 3) * 16 + l15;   // A-frag row
  const int nbase = (wave >> 2) * 32;       // this wave's n-offset (0 / 32)

  float4v acc0 = {0.f, 0.f, 0.f, 0.f};
  float4v acc1 = {0.f, 0.f, 0.f, 0.f};

  // prologue: prefetch tile 0
  float4 a0 = *(const float4*)(aptr);
  float4 a1 = *(const float4*)(aptr + (size_t)32 * NROWS);
  int4v bv = *(const int4v*)(bptr);

  for (int kt = 0; kt < NROWS / 64; ++kt) {
    __syncthreads();
    {
      half4 s0, s1;
      s0.x = f2h(a0.x); s0.y = f2h(a0.y); s0.z = f2h(a0.z); s0.w = f2h(a0.w);
      s1.x = f2h(a1.x); s1.y = f2h(a1.y); s1.z = f2h(a1.z); s1.w = f2h(a1.w);
      *(half4*)&As[ar0 * LDSTRIDE + akc * 4] = s0;
      *(half4*)&As[(ar0 + 32) * LDSTRIDE + akc * 4] = s1;
      *(int4v*)&Bs[bn * LDSTRIDE + bc * 8] = bv;
    }
    __syncthreads();
    if (kt != NROWS / 64 - 1) {              // prefetch next K-tile
      const float* ap = aptr + (size_t)(kt + 1) * 64;
      a0 = *(const float4*)(ap);
      a1 = *(const float4*)(ap + (size_t)32 * NROWS);
      bv = *(const int4v*)(bptr + (size_t)(kt + 1) * 64);
    }
#pragma unroll
    for (int ks = 0; ks < 64; ks += 32) {
      half8 af  = *(const half8*)&As[mrow * LDSTRIDE + ks + quad * 8];
      half8 bf0 = *(const half8*)&Bs[(nbase + l15) * LDSTRIDE + ks + quad * 8];
      half8 bf1 = *(const half8*)&Bs[(nbase + 16 + l15) * LDSTRIDE + ks + quad * 8];
      acc0 = mfma16(af, bf0, acc0);
      acc1 = mfma16(af, bf1, acc1);
    }
  }
  // epilogue: C/D layout col = lane&15, row = quad*4 + reg
  const int orow = m0 + (wave & 3) * 16 + quad * 4;
#pragma unroll
  for (int r = 0; r < 4; ++r) {
    g[(size_t)(orow + r) * HIDDIM + nbase + l15] = acc0[r];
    g[(size_t)(orow + r) * HIDDIM + nbase + 16 + l15] = acc1[r];
  }
}

// ---------------- S: fused gates. Z=[ht|g] (fp16) @ Wc^T + eltwise ----------
#define ZSTRIDE 136
__global__ __launch_bounds__(256) void gates(const float* __restrict__ ht,
                                             const float* __restrict__ g,
                                             const float* __restrict__ Ct_1,
                                             const half_t* __restrict__ Wc,
                                             const float* __restrict__ biasc,
                                             float* __restrict__ out) {
  __shared__ half_t Zs[64 * ZSTRIDE];
  __shared__ float bias_s[256];
  const int t = threadIdx.x;
  const int m0 = blockIdx.x * 64;
  bias_s[t] = biasc[t];
#pragma unroll
  for (int i = 0; i < 4; ++i) {
    int c = i * 256 + t;             // 0..1023 : row = c>>4, chunk = c&15
    int row = c >> 4, kc = c & 15;
    float4 hv = *(const float4*)(ht + (size_t)(m0 + row) * 64 + kc * 4);
    float4 gv = *(const float4*)(g + (size_t)(m0 + row) * 64 + kc * 4);
    half4 hs, gs;
    hs.x = f2h(hv.x); hs.y = f2h(hv.y); hs.z = f2h(hv.z); hs.w = f2h(hv.w);
    gs.x = f2h(gv.x); gs.y = f2h(gv.y); gs.z = f2h(gv.z); gs.w = f2h(gv.w);
    *(half4*)&Zs[row * ZSTRIDE + kc * 4] = hs;
    *(half4*)&Zs[row * ZSTRIDE + 64 + kc * 4] = gs;
  }
  __syncthreads();
  const int lane = t & 63, wave = t >> 6;
  const int quad = lane >> 4, l15 = lane & 15;
  const int mo = wave * 16;

  half8 af[4];
#pragma unroll
  for (int ks = 0; ks < 4; ++ks)
    af[ks] = *(const half8*)&Zs[(mo + l15) * ZSTRIDE + ks * 32 + quad * 8];

  float4v acc[16];
#pragma unroll
  for (int nt = 0; nt < 16; ++nt) acc[nt] = (float4v){0.f, 0.f, 0.f, 0.f};
#pragma unroll
  for (int nt = 0; nt < 16; ++nt) {
    const half_t* wp = Wc + (size_t)(nt * 16 + l15) * 128 + quad * 8;
#pragma unroll
    for (int ks = 0; ks < 4; ++ks) {
      half8 bf = *(const half8*)(wp + ks * 32);
      acc[nt] = mfma16(af[ks], bf, acc[nt]);
    }
  }
  const size_t NH = (size_t)NROWS * HIDDIM;
#pragma unroll
  for (int th = 0; th < 4; ++th) {
    int h = th * 16 + l15;
#pragma unroll
    for (int r = 0; r < 4; ++r) {
      int row = m0 + mo + quad * 4 + r;
      float ip = acc[th][r]      + bias_s[h];
      float fp = acc[4 + th][r]  + bias_s[64 + h];
      float op = acc[8 + th][r]  + bias_s[128 + h];
      float up = acc[12 + th][r] + bias_s[192 + h];
      float c1 = Ct_1[(size_t)row * 64 + h];
      float it = 1.f / (1.f + __expf(-ip));
      float ft = 1.f / (1.f + __expf(-fp));
      float ot = 1.f / (1.f + __expf(-op));
      float ut = 1.f - 2.f / (__expf(2.f * up) + 1.f);   // tanh, saturation-safe
      float Ct = ft * c1 + it * ut;
      float tC = 1.f - 2.f / (__expf(2.f * Ct) + 1.f);
      float Ht = ot * tC;
      out[(size_t)row * 64 + h] = Ht;
      out[NH + (size_t)row * 64 + h] = Ct;
    }
  }
}

extern "C" void kernel_launch(void* const* d_in, const int* in_sizes, int n_in,
                              void* d_out, int out_size, void* d_ws, size_t ws_size,
                              hipStream_t stream) {
  const float* ht   = (const float*)d_in[0];
  const float* Ht_1 = (const float*)d_in[1];
  const float* Ct_1 = (const float*)d_in[2];
  const float* adj  = (const float*)d_in[3];

  char* ws = (char*)d_ws;
  float* g      = (float*)ws;                       // 4 MiB
  half_t* Bt    = (half_t*)(ws + 4194304);          // 2 MiB
  half_t* Wc    = (half_t*)(ws + 6291456);          // 64 KiB
  float* biasc  = (float*)(ws + 6356992);           // 1 KiB

  prep_wb<<<129, 256, 0, stream>>>(
      (const float*)d_in[4],  (const float*)d_in[6],
      (const float*)d_in[8],  (const float*)d_in[10],
      (const float*)d_in[12], (const float*)d_in[14],
      (const float*)d_in[16], (const float*)d_in[18],
      (const float*)d_in[5],  (const float*)d_in[7],
      (const float*)d_in[9],  (const float*)d_in[11],
      (const float*)d_in[13], (const float*)d_in[15],
      (const float*)d_in[17], (const float*)d_in[19],
      Wc, biasc);
  prep_bt<<<256, 256, 0, stream>>>(Ht_1, Bt);
  gconv<<<256, 512, 0, stream>>>(adj, Bt, g);
  gates<<<256, 256, 0, stream>>>(ht, g, Ct_1, Wc, biasc, (float*)d_out);
}